// Round 5
// baseline (471.727 us; speedup 1.0000x reference)
//
#include <hip/hip_runtime.h>
#include <math.h>

// Problem constants (unit_gcn): N=64, C=64, T=300, V=25, S=3
//
// ws float layout (needs only 48,128 bytes; harness provides >=61.5MB per R4):
//   [2048, 4096)   : stats, 16 replicas x (sum[64], sumsq[64])
//   [4352, 10496)  : W-frag table ushort[12288]: frag f=((s*2+kt)*4+wv), elem lane*8+j
//   [10496, 12032) : A-frag table ushort[3072]:  frag f=(s*2+nt2)
//
// Scheme: BN batch stats require all of y, but y never needs HBM:
//   pass1: GEMM -> y in regs -> per-channel sum/sumsq atomics only (~1MB written)
//   pass2: recompute identical y (same tables/rounding -> bitwise equal),
//          apply BN+ReLU+residual (residual read from the staged X LDS tile),
//          write out once. Bias b.sum(0) cancels through BN -> dropped.

typedef __attribute__((ext_vector_type(8))) short bf16x8;
typedef __attribute__((ext_vector_type(4))) float f32x4;

__device__ inline ushort f2bf(float f) {
    union { float f; unsigned u; } v; v.f = f;
    unsigned r = v.u + 0x7fffu + ((v.u >> 16) & 1u);
    return (ushort)(r >> 16);
}
__device__ inline float bf2f(ushort h) {
    union { unsigned u; float f; } v; v.u = ((unsigned)h) << 16;
    return v.f;
}

// ---------------------------------------------------------------------------
// K1: 8 blocks. Normalize A (LDS), zero stats (block 0), build frag tables.
// ---------------------------------------------------------------------------
__global__ __launch_bounds__(256) void k_prep(const float* __restrict__ PA,
                                              const float* __restrict__ W,
                                              float* __restrict__ ws) {
    __shared__ float Al[1875];
    const int tid = threadIdx.x;
    const int bid = blockIdx.x;
    for (int i = tid; i < 1875; i += 256) Al[i] = PA[i];
    if (bid == 0)
        for (int i = tid; i < 2048; i += 256) ws[2048 + i] = 0.0f;
    __syncthreads();
    if (tid < 75) {
        int s = tid / 25, w = tid - s * 25;
        float ss = 0.0f;
        for (int v = 0; v < 25; ++v) {
            float p = Al[s * 625 + v * 25 + w];
            ss += p * p;
        }
        float inv = 1.0f / (sqrtf(ss) + 1e-4f);
        for (int v = 0; v < 25; ++v) Al[s * 625 + v * 25 + w] *= inv;
    }
    __syncthreads();
    int idx = bid * 256 + tid;
    if (idx < 1536) {  // W-frag: W[s][o=wv*16+col][c=kt*32+quad*8+j]
        ushort* wt = (ushort*)(ws + 4352);
        int lane = idx & 63, rest = idx >> 6;
        int wv = rest & 3, sk = rest >> 2;
        int kt = sk & 1, s = sk >> 1;
        int col = lane & 15, quad = lane >> 4;
        const float* wp = W + s * 4096 + (wv * 16 + col) * 64 + kt * 32 + quad * 8;
#pragma unroll
        for (int j = 0; j < 8; ++j) wt[idx * 8 + j] = f2bf(wp[j]);
    } else if (idx < 1920) {  // A-frag: A[s][v=quad*8+j][w=nt2*16+col], OOB->0
        ushort* at = (ushort*)(ws + 10496);
        int a = idx - 1536;
        int lane = a & 63, rest = a >> 6;
        int nt2 = rest & 1, s = rest >> 1;
        int col = lane & 15, quad = lane >> 4;
        int w = nt2 * 16 + col;
#pragma unroll
        for (int j = 0; j < 8; ++j) {
            int v = quad * 8 + j;
            float av = (v < 25 && w < 25) ? Al[s * 625 + v * 25 + w] : 0.0f;
            at[a * 8 + j] = f2bf(av);
        }
    }
}

// ---------------------------------------------------------------------------
// Shared GEMM body (pass1/pass2), per block: one n, 5 t-steps.
//  GEMM1 (per s,t): Zt[o, v] = sum_c W_s[o,c] X[c, t*25+v]   (N=32, v<25 kept)
//  GEMM2 (per s,t): yacc[t] += Zt * A_s                       (K=25->32 pad)
// LDS: Xl [132 rows][72] bf16 (rows 125..131 zero; 16B-aligned rows, small
// conflicts only), Zl [64][40] bf16 (cols 25..39 zero). Each wave owns o-strip
// [wv*16, wv*16+16) and round-trips only its own Z rows -> no inner barrier.
// LDS ~25KB -> 6 blocks/CU resident (2x R4) for latency hiding.
// ---------------------------------------------------------------------------
#define GEMM_PROLOGUE_AND_BODY                                                  \
    const int tid = threadIdx.x;                                                \
    const int wv = tid >> 6;                                                    \
    const int lane = tid & 63;                                                  \
    const int col = lane & 15;                                                  \
    const int quad = lane >> 4;                                                 \
    const int strip = wv << 4;                                                  \
    const int n = blockIdx.y;                                                   \
    const int t0 = blockIdx.x * 5;                                              \
    const ushort* wt = (const ushort*)(ws + 4352);                              \
    const ushort* at = (const ushort*)(ws + 10496);                             \
    bf16x8 wf[3][2], af[3][2];                                                  \
    _Pragma("unroll") for (int s = 0; s < 3; ++s) {                             \
        _Pragma("unroll") for (int kt = 0; kt < 2; ++kt)                        \
            wf[s][kt] = *(const bf16x8*)&wt[(((s * 2 + kt) * 4 + wv) * 64 + lane) * 8]; \
        _Pragma("unroll") for (int nt2 = 0; nt2 < 2; ++nt2)                     \
            af[s][nt2] = *(const bf16x8*)&at[((s * 2 + nt2) * 64 + lane) * 8];  \
    }                                                                           \
    {                                                                           \
        const float* xp = x + n * 480000 + t0 * 25;                             \
        _Pragma("unroll 8") for (int i = tid; i < 8192; i += 256) {             \
            int c = i >> 7, tv = i & 127;                                       \
            float g = (tv < 125) ? xp[c * 7500 + tv] : 0.0f;                    \
            Xl[tv * 72 + c] = f2bf(g);                                          \
        }                                                                       \
        for (int i = tid; i < 288; i += 256) Xl[128 * 72 + i] = 0;              \
        for (int i = tid; i < 1280; i += 256) ((unsigned*)Zl)[i] = 0;           \
    }                                                                           \
    f32x4 yacc[5][2];                                                           \
    _Pragma("unroll") for (int t = 0; t < 5; ++t)                               \
        _Pragma("unroll") for (int j = 0; j < 2; ++j)                           \
            yacc[t][j] = (f32x4){0.f, 0.f, 0.f, 0.f};

#define GEMM_SLOOP                                                              \
    _Pragma("unroll") for (int s = 0; s < 3; ++s) {                             \
        _Pragma("unroll") for (int t = 0; t < 5; ++t) {                         \
            const int r0 = (t * 25 + col) * 72 + (quad << 3);                   \
            const int r1 = r0 + 16 * 72;                                        \
            bf16x8 x00 = *(const bf16x8*)&Xl[r0];                               \
            bf16x8 x01 = *(const bf16x8*)&Xl[r0 + 32];                          \
            bf16x8 x10 = *(const bf16x8*)&Xl[r1];                               \
            bf16x8 x11 = *(const bf16x8*)&Xl[r1 + 32];                          \
            f32x4 z0 = (f32x4){0.f, 0.f, 0.f, 0.f};                             \
            f32x4 z1 = (f32x4){0.f, 0.f, 0.f, 0.f};                             \
            z0 = __builtin_amdgcn_mfma_f32_16x16x32_bf16(wf[s][0], x00, z0, 0, 0, 0); \
            z0 = __builtin_amdgcn_mfma_f32_16x16x32_bf16(wf[s][1], x01, z0, 0, 0, 0); \
            z1 = __builtin_amdgcn_mfma_f32_16x16x32_bf16(wf[s][0], x10, z1, 0, 0, 0); \
            z1 = __builtin_amdgcn_mfma_f32_16x16x32_bf16(wf[s][1], x11, z1, 0, 0, 0); \
            const int zrow = strip + (quad << 2);                               \
            _Pragma("unroll") for (int r = 0; r < 4; ++r)                       \
                Zl[(zrow + r) * 40 + col] = f2bf(z0[r]);                        \
            if (col < 9) {                                                      \
                _Pragma("unroll") for (int r = 0; r < 4; ++r)                   \
                    Zl[(zrow + r) * 40 + 16 + col] = f2bf(z1[r]);               \
            }                                                                   \
            bf16x8 zf = *(const bf16x8*)&Zl[(strip + col) * 40 + (quad << 3)];  \
            yacc[t][0] = __builtin_amdgcn_mfma_f32_16x16x32_bf16(zf, af[s][0], yacc[t][0], 0, 0, 0); \
            yacc[t][1] = __builtin_amdgcn_mfma_f32_16x16x32_bf16(zf, af[s][1], yacc[t][1], 0, 0, 0); \
        }                                                                       \
    }

// ---------------------------------------------------------------------------
// K2: pass 1 — stats only. No y materialization.
// ---------------------------------------------------------------------------
__global__ __launch_bounds__(256) void k_pass1(const float* __restrict__ x,
                                               const float* __restrict__ ws,
                                               float* __restrict__ stats) {
    __shared__ __align__(16) ushort Xl[132 * 72];
    __shared__ __align__(16) ushort Zl[64 * 40];
    GEMM_PROLOGUE_AND_BODY
    __syncthreads();
    GEMM_SLOOP

    float ssum[4] = {0.f, 0.f, 0.f, 0.f}, ssq[4] = {0.f, 0.f, 0.f, 0.f};
#pragma unroll
    for (int t = 0; t < 5; ++t)
#pragma unroll
        for (int nt2 = 0; nt2 < 2; ++nt2) {
            int w = nt2 * 16 + col;
            if (w < 25) {
#pragma unroll
                for (int r = 0; r < 4; ++r) {
                    float yv = yacc[t][nt2][r];
                    ssum[r] += yv;
                    ssq[r] = fmaf(yv, yv, ssq[r]);
                }
            }
        }
    const int obase = strip + (quad << 2);
    const int rep = (blockIdx.x + blockIdx.y) & 15;
#pragma unroll
    for (int r = 0; r < 4; ++r) {
        float a = ssum[r], b = ssq[r];
        for (int m = 1; m < 16; m <<= 1) {  // reduce over the 16 w-lanes
            a += __shfl_xor(a, m, 64);
            b += __shfl_xor(b, m, 64);
        }
        if (col == 0) {
            atomicAdd(&stats[rep * 128 + obase + r], a);
            atomicAdd(&stats[rep * 128 + 64 + obase + r], b);
        }
    }
}

// ---------------------------------------------------------------------------
// K3: pass 2 — recompute y (bitwise-identical), fold BN+ReLU+residual, write
// out. BN scale/shift computed per-block from stats (no extra kernel);
// residual taken from the staged X LDS tile (bf16, error <= 0.004|x|).
// ---------------------------------------------------------------------------
__global__ __launch_bounds__(256) void k_pass2(const float* __restrict__ x,
                                               const float* __restrict__ ws,
                                               const float* __restrict__ stats,
                                               const float* __restrict__ gamma,
                                               const float* __restrict__ beta,
                                               float* __restrict__ out) {
    __shared__ __align__(16) ushort Xl[132 * 72];
    __shared__ __align__(16) ushort Zl[64 * 40];
    __shared__ float sred[128];
    __shared__ float scl[64], sft[64];
    GEMM_PROLOGUE_AND_BODY
    if (tid < 128) {
        float acc = 0.0f;
        for (int rp = 0; rp < 16; ++rp) acc += stats[rp * 128 + tid];
        sred[tid] = acc;
    }
    __syncthreads();
    if (tid < 64) {
        const float invn = 1.0f / 480000.0f;  // N*T*V
        float mean = sred[tid] * invn;
        float var = sred[64 + tid] * invn - mean * mean;
        float sc = gamma[tid] * rsqrtf(var + 1e-5f);
        scl[tid] = sc;
        sft[tid] = beta[tid] - mean * sc;
    }
    __syncthreads();
    GEMM_SLOOP

    const int obase = strip + (quad << 2);
    float sc[4], sh[4];
#pragma unroll
    for (int r = 0; r < 4; ++r) { sc[r] = scl[obase + r]; sh[r] = sft[obase + r]; }
#pragma unroll
    for (int t = 0; t < 5; ++t)
#pragma unroll
        for (int nt2 = 0; nt2 < 2; ++nt2) {
            int w = nt2 * 16 + col;
            if (w < 25) {
                float* op = out + n * 480000 + obase * 7500 + (t0 + t) * 25 + w;
                const int xr = (t * 25 + w) * 72 + obase;
#pragma unroll
                for (int r = 0; r < 4; ++r) {
                    float res = bf2f(Xl[xr + r]);
                    float yv = fmaf(yacc[t][nt2][r], sc[r], sh[r]) + res;
                    op[r * 7500] = fmaxf(yv, 0.0f);
                }
            }
        }
}

// ---------------------------------------------------------------------------
extern "C" void kernel_launch(void* const* d_in, const int* in_sizes, int n_in,
                              void* d_out, int out_size, void* d_ws, size_t ws_size,
                              hipStream_t stream) {
    const float* x = (const float*)d_in[0];
    const float* PA = (const float*)d_in[1];
    const float* W = (const float*)d_in[2];
    // d_in[3] = b : cancels through training-mode BN -> unused
    const float* gamma = (const float*)d_in[4];
    const float* beta = (const float*)d_in[5];
    float* wsf = (float*)d_ws;
    float* out = (float*)d_out;

    k_prep<<<8, 256, 0, stream>>>(PA, W, wsf);
    dim3 g(60, 64);
    k_pass1<<<g, 256, 0, stream>>>(x, wsf, wsf + 2048);
    k_pass2<<<g, 256, 0, stream>>>(x, wsf, wsf + 2048, gamma, beta, out);
}

// Round 6
// 387.579 us; speedup vs baseline: 1.2171x; 1.2171x over previous
//
#include <hip/hip_runtime.h>
#include <math.h>

// Problem constants (unit_gcn): N=64, C=64, T=300, V=25, S=3
//
// ws float layout:
//   [2048, 4096)   : stats, 16 replicas x (sum[64], sumsq[64])
//   [4096, 4224)   : scale[64], shift[64]
//   [4352, 10496)  : W-frag table ushort[12288]: frag f=((s*2+kt)*4+wv), elem lane*8+j
//   [10496, 12032) : A-frag table ushort[3072]:  frag f=(s*2+nt2)
//   byte 65536+    : ypre bf16, natural [n][o][t][w], 61.44 MB
//
// R6 theory: all prior rounds were latency-bound at ~2 waves/SIMD because the
// unified VGPR+AGPR budget (~200 regs: 12 hoisted frags=48 + yacc=40 + temps)
// capped residency. Cut live regs (per-s frag reload, t=4 -> yacc 32) to get
// ~5 waves/SIMD. Bias b.sum(0) cancels through training-mode BN -> dropped.

typedef __attribute__((ext_vector_type(8))) short bf16x8;
typedef __attribute__((ext_vector_type(4))) float f32x4;

__device__ inline ushort f2bf(float f) {
    union { float f; unsigned u; } v; v.f = f;
    unsigned r = v.u + 0x7fffu + ((v.u >> 16) & 1u);
    return (ushort)(r >> 16);
}
__device__ inline float bf2f(ushort h) {
    union { unsigned u; float f; } v; v.u = ((unsigned)h) << 16;
    return v.f;
}

// ---------------------------------------------------------------------------
// K1: 8 blocks. Normalize A (LDS), zero stats (block 0), build frag tables.
// ---------------------------------------------------------------------------
__global__ __launch_bounds__(256) void k_prep(const float* __restrict__ PA,
                                              const float* __restrict__ W,
                                              float* __restrict__ ws) {
    __shared__ float Al[1875];
    const int tid = threadIdx.x;
    const int bid = blockIdx.x;
    for (int i = tid; i < 1875; i += 256) Al[i] = PA[i];
    if (bid == 0)
        for (int i = tid; i < 2048; i += 256) ws[2048 + i] = 0.0f;
    __syncthreads();
    if (tid < 75) {
        int s = tid / 25, w = tid - s * 25;
        float ss = 0.0f;
        for (int v = 0; v < 25; ++v) {
            float p = Al[s * 625 + v * 25 + w];
            ss += p * p;
        }
        float inv = 1.0f / (sqrtf(ss) + 1e-4f);
        for (int v = 0; v < 25; ++v) Al[s * 625 + v * 25 + w] *= inv;
    }
    __syncthreads();
    int idx = bid * 256 + tid;
    if (idx < 1536) {  // W-frag: W[s][o=wv*16+col][c=kt*32+quad*8+j]
        ushort* wt = (ushort*)(ws + 4352);
        int lane = idx & 63, rest = idx >> 6;
        int wv = rest & 3, sk = rest >> 2;
        int kt = sk & 1, s = sk >> 1;
        int col = lane & 15, quad = lane >> 4;
        const float* wp = W + s * 4096 + (wv * 16 + col) * 64 + kt * 32 + quad * 8;
#pragma unroll
        for (int j = 0; j < 8; ++j) wt[idx * 8 + j] = f2bf(wp[j]);
    } else if (idx < 1920) {  // A-frag: A[s][v=quad*8+j][w=nt2*16+col], OOB->0
        ushort* at = (ushort*)(ws + 10496);
        int a = idx - 1536;
        int lane = a & 63, rest = a >> 6;
        int nt2 = rest & 1, s = rest >> 1;
        int col = lane & 15, quad = lane >> 4;
        int w = nt2 * 16 + col;
#pragma unroll
        for (int j = 0; j < 8; ++j) {
            int v = quad * 8 + j;
            float av = (v < 25 && w < 25) ? Al[s * 625 + v * 25 + w] : 0.0f;
            at[a * 8 + j] = f2bf(av);
        }
    }
}

// ---------------------------------------------------------------------------
// K2: per block one n, 4 t-steps (grid 75 x 64).
//  GEMM1 (per s,t): Zt[o, v] = sum_c W_s[o,c] X[c, t*25+v]   (N=32)
//  GEMM2 (per s,t): yacc[t] += Zt * A_s                       (K=25->32 pad)
// Frags reloaded per s (L3-hot) -> live regs ~90 -> ~5 waves/SIMD resident.
// LDS: Xl [112 rows][72] bf16 (rows 100..111 zero), Zl [64][40] bf16.
// Each wave owns o-strip [wv*16, wv*16+16): round-trips only its own Z rows.
// Writes ypre bf16 + per-channel sum/sumsq into 16 replica atomic lines.
// ---------------------------------------------------------------------------
__global__ __launch_bounds__(256, 4) void k_main6(const float* __restrict__ x,
                                                  const float* __restrict__ ws,
                                                  ushort* __restrict__ ypre,
                                                  float* __restrict__ stats) {
    __shared__ __align__(16) ushort Xl[112 * 72];
    __shared__ __align__(16) ushort Zl[64 * 40];
    __shared__ float sst[128];

    const int tid = threadIdx.x;
    const int wv = tid >> 6;
    const int lane = tid & 63;
    const int col = lane & 15;
    const int quad = lane >> 4;
    const int strip = wv << 4;
    const int n = blockIdx.y;
    const int t0 = blockIdx.x * 4;

    // stage X: x[n, c, t0*25 + tv] -> Xl[tv*72 + c]; tv in [100,112) zero
    {
        const float* xp = x + n * 480000 + t0 * 25;
#pragma unroll 8
        for (int i = tid; i < 8192; i += 256) {
            int c = i >> 7, tv = i & 127;
            if (tv < 112) Xl[tv * 72 + c] = (tv < 100) ? f2bf(xp[c * 7500 + tv]) : 0;
        }
    }
    for (int i = tid; i < 1280; i += 256) ((unsigned*)Zl)[i] = 0;  // all of Zl
    __syncthreads();

    const ushort* wt = (const ushort*)(ws + 4352);
    const ushort* at = (const ushort*)(ws + 10496);

    f32x4 yacc[4][2];
#pragma unroll
    for (int t = 0; t < 4; ++t)
#pragma unroll
        for (int j = 0; j < 2; ++j) yacc[t][j] = (f32x4){0.f, 0.f, 0.f, 0.f};

    for (int s = 0; s < 3; ++s) {
        // reload only the current-s fragments (16 live regs, L3-hot)
        bf16x8 wf0 = *(const bf16x8*)&wt[(((s * 2 + 0) * 4 + wv) * 64 + lane) * 8];
        bf16x8 wf1 = *(const bf16x8*)&wt[(((s * 2 + 1) * 4 + wv) * 64 + lane) * 8];
        bf16x8 af0 = *(const bf16x8*)&at[((s * 2 + 0) * 64 + lane) * 8];
        bf16x8 af1 = *(const bf16x8*)&at[((s * 2 + 1) * 64 + lane) * 8];
#pragma unroll
        for (int t = 0; t < 4; ++t) {
            const int r0 = (t * 25 + col) * 72 + (quad << 3);
            const int r1 = r0 + 16 * 72;
            bf16x8 x00 = *(const bf16x8*)&Xl[r0];
            bf16x8 x01 = *(const bf16x8*)&Xl[r0 + 32];
            bf16x8 x10 = *(const bf16x8*)&Xl[r1];
            bf16x8 x11 = *(const bf16x8*)&Xl[r1 + 32];
            f32x4 z0 = (f32x4){0.f, 0.f, 0.f, 0.f};
            f32x4 z1 = (f32x4){0.f, 0.f, 0.f, 0.f};
            z0 = __builtin_amdgcn_mfma_f32_16x16x32_bf16(wf0, x00, z0, 0, 0, 0);
            z0 = __builtin_amdgcn_mfma_f32_16x16x32_bf16(wf1, x01, z0, 0, 0, 0);
            z1 = __builtin_amdgcn_mfma_f32_16x16x32_bf16(wf0, x10, z1, 0, 0, 0);
            z1 = __builtin_amdgcn_mfma_f32_16x16x32_bf16(wf1, x11, z1, 0, 0, 0);
            const int zrow = strip + (quad << 2);
#pragma unroll
            for (int r = 0; r < 4; ++r) Zl[(zrow + r) * 40 + col] = f2bf(z0[r]);
            if (col < 9) {
#pragma unroll
                for (int r = 0; r < 4; ++r) Zl[(zrow + r) * 40 + 16 + col] = f2bf(z1[r]);
            }
            bf16x8 zf = *(const bf16x8*)&Zl[(strip + col) * 40 + (quad << 3)];
            yacc[t][0] = __builtin_amdgcn_mfma_f32_16x16x32_bf16(zf, af0, yacc[t][0], 0, 0, 0);
            yacc[t][1] = __builtin_amdgcn_mfma_f32_16x16x32_bf16(zf, af1, yacc[t][1], 0, 0, 0);
        }
    }

    // epilogue: D layout col(lane&15)=w(+16*nt2), row(quad*4+r)=o offset
    float ssum[4] = {0.f, 0.f, 0.f, 0.f}, ssq[4] = {0.f, 0.f, 0.f, 0.f};
    const int obase = strip + (quad << 2);
#pragma unroll
    for (int t = 0; t < 4; ++t)
#pragma unroll
        for (int nt2 = 0; nt2 < 2; ++nt2) {
            int w = nt2 * 16 + col;
            if (w < 25) {
                ushort* yp = ypre + n * 480000 + obase * 7500 + (t0 + t) * 25 + w;
                f32x4 f = yacc[t][nt2];
#pragma unroll
                for (int r = 0; r < 4; ++r) {
                    float yv = f[r];
                    yp[r * 7500] = f2bf(yv);
                    ssum[r] += yv;
                    ssq[r] = fmaf(yv, yv, ssq[r]);
                }
            }
        }
#pragma unroll
    for (int r = 0; r < 4; ++r) {
        float a = ssum[r], b = ssq[r];
        for (int m = 1; m < 16; m <<= 1) {  // reduce over the 16 w-lanes
            a += __shfl_xor(a, m, 64);
            b += __shfl_xor(b, m, 64);
        }
        if (col == 0) {  // unique (wv,quad,r) -> unique o
            sst[obase + r] = a;
            sst[64 + obase + r] = b;
        }
    }
    __syncthreads();
    const int rep = (blockIdx.x + blockIdx.y) & 15;
    if (tid < 128) atomicAdd(&stats[rep * 128 + tid], sst[tid]);
}

// ---------------------------------------------------------------------------
// K3: finalize BN scale/shift (16 replica lines of 128)
// ---------------------------------------------------------------------------
__global__ void k_stats(const float* __restrict__ stats,
                        const float* __restrict__ gamma,
                        const float* __restrict__ beta,
                        float* __restrict__ scsh) {
    int o = threadIdx.x;
    if (o >= 64) return;
    float su = 0.f, sq = 0.f;
    for (int r = 0; r < 16; ++r) {
        su += stats[r * 128 + o];
        sq += stats[r * 128 + 64 + o];
    }
    const float invn = 1.0f / 480000.0f;  // N*T*V
    float mean = su * invn;
    float var = sq * invn - mean * mean;
    float inv = rsqrtf(var + 1e-5f);
    float sc = gamma[o] * inv;
    scsh[o] = sc;
    scsh[64 + o] = beta[o] - mean * sc;
}

// ---------------------------------------------------------------------------
// K4: out = relu(sc[o]*bf2f(ypre) + sh[o] + x). Plane-mapped: block = one
// (n,o) plane (4096 blocks), o = blockIdx&63, pure streaming.
// ---------------------------------------------------------------------------
__global__ __launch_bounds__(256) void k_bnrelu_a(const float* __restrict__ x,
                                                  const ushort* __restrict__ ypre,
                                                  const float* __restrict__ scsh,
                                                  float* __restrict__ out) {
    const int plane = blockIdx.x;  // n*64 + o
    const int o = plane & 63;
    const float sc = scsh[o], sh = scsh[64 + o];
    const ushort* yp = ypre + plane * 7500;
    const float4* xp = (const float4*)(x + plane * 7500);
    float4* op = (float4*)(out + plane * 7500);
    for (int j = threadIdx.x; j < 1875; j += 256) {
        ushort4 yv = ((const ushort4*)yp)[j];
        float4 xx = xp[j];
        float4 r;
        r.x = fmaxf(fmaf(bf2f(yv.x), sc, sh) + xx.x, 0.0f);
        r.y = fmaxf(fmaf(bf2f(yv.y), sc, sh) + xx.y, 0.0f);
        r.z = fmaxf(fmaf(bf2f(yv.z), sc, sh) + xx.z, 0.0f);
        r.w = fmaxf(fmaf(bf2f(yv.w), sc, sh) + xx.w, 0.0f);
        op[j] = r;
    }
}

// ---------------------------------------------------------------------------
extern "C" void kernel_launch(void* const* d_in, const int* in_sizes, int n_in,
                              void* d_out, int out_size, void* d_ws, size_t ws_size,
                              hipStream_t stream) {
    const float* x = (const float*)d_in[0];
    const float* PA = (const float*)d_in[1];
    const float* W = (const float*)d_in[2];
    // d_in[3] = b : cancels through training-mode BN -> unused
    const float* gamma = (const float*)d_in[4];
    const float* beta = (const float*)d_in[5];
    float* wsf = (float*)d_ws;
    float* out = (float*)d_out;
    ushort* ypre = (ushort*)((char*)d_ws + 65536);

    k_prep<<<8, 256, 0, stream>>>(PA, W, wsf);
    dim3 g(75, 64);
    k_main6<<<g, 256, 0, stream>>>(x, wsf, ypre, wsf + 2048);
    k_stats<<<1, 64, 0, stream>>>(wsf + 2048, gamma, beta, wsf + 4096);
    k_bnrelu_a<<<4096, 256, 0, stream>>>(x, ypre, wsf + 4096, out);
}